// Round 8
// baseline (1233.716 us; speedup 1.0000x reference)
//
#include <hip/hip_runtime.h>
#include <math.h>

// AttnBlock fused pipeline, round 8: flash rebuilt on 32x32x16 MFMA
// (halves LDS reads per query — the r7 bottleneck), 128q blocks, 1 block/CU,
// double-buffered K/V staging (r6 pattern, now with 512-VGPR budget -> no spill).
//   x,y: [8, 256, 64, 64] fp32; GN groups=4 eps=1e-6; 4 conv1x1 weights [256,256].
// Fragment conventions (HW-validated r3/r5/r7 for 16x16; 32x32 D-layout per
// guide m74/m101: col=lane&31, row=(reg&3)+8*(reg>>2)+4*(lane>>5)):
//   32x32 A-frag: row = lane&31, k-slice = (lane>>5)*8
//   32x32 B-frag: col = lane&31, k-slice = (lane>>5)*8
// Workspace: Q,K (bf16 [p][c]), V (bf16 [c][p]) 16MB each + Ot (fp32 32MB) + stats.

namespace {
constexpr int kB   = 8;
constexpr int kC   = 256;
constexpr int kCPG = 64;
constexpr int kHW  = 4096;
constexpr float kEps = 1e-6f;
}

typedef short bf16x8 __attribute__((ext_vector_type(8)));   // 8 bf16 in 4 VGPRs
typedef float f32x4  __attribute__((ext_vector_type(4)));
typedef float f32x16 __attribute__((ext_vector_type(16)));

#define MFMA16(a, b, c) __builtin_amdgcn_mfma_f32_16x16x32_bf16((a), (b), (c), 0, 0, 0)
#define MFMA32(a, b, c) __builtin_amdgcn_mfma_f32_32x32x16_bf16((a), (b), (c), 0, 0, 0)

__device__ __forceinline__ unsigned short f2bf(float v) {   // RNE fp32 -> bf16 bits
  unsigned u = __float_as_uint(v);
  u += 0x7FFFu + ((u >> 16) & 1u);
  return (unsigned short)(u >> 16);
}
__device__ __forceinline__ float bf2f(unsigned short h) {
  return __uint_as_float(((unsigned)h) << 16);
}

// ---------------------------------------------------------------------------
// Kernel 1: GroupNorm statistics -> per-(tensor,b,c) scale/shift (unchanged)
// ---------------------------------------------------------------------------
__global__ __launch_bounds__(256)
void gn_stats_kernel(const float* __restrict__ x, const float* __restrict__ y,
                     const float* __restrict__ gamma, const float* __restrict__ beta,
                     float* __restrict__ scaleX, float* __restrict__ shiftX,
                     float* __restrict__ scaleY, float* __restrict__ shiftY) {
  int blk = blockIdx.x;            // t*32 + b*4 + g
  int g = blk & 3;
  int b = (blk >> 2) & 7;
  int t = blk >> 5;
  const float* src = (t == 0 ? x : y) + ((size_t)b * kC + (size_t)g * kCPG) * kHW;
  const int N = kCPG * kHW;
  float sum = 0.f, ssq = 0.f;
  for (int i = threadIdx.x * 4; i < N; i += 256 * 4) {
    float4 v = *(const float4*)(src + i);
    sum += v.x + v.y + v.z + v.w;
    ssq += v.x * v.x + v.y * v.y + v.z * v.z + v.w * v.w;
  }
  #pragma unroll
  for (int off = 32; off > 0; off >>= 1) {
    sum += __shfl_down(sum, off);
    ssq += __shfl_down(ssq, off);
  }
  __shared__ float rs[4], rq[4];
  __shared__ float sM, sR;
  int lane = threadIdx.x & 63, w = threadIdx.x >> 6;
  if (lane == 0) { rs[w] = sum; rq[w] = ssq; }
  __syncthreads();
  if (threadIdx.x == 0) {
    float s = rs[0] + rs[1] + rs[2] + rs[3];
    float q = rq[0] + rq[1] + rq[2] + rq[3];
    float mean = s / (float)N;
    float var  = q / (float)N - mean * mean;
    sM = mean;
    sR = rsqrtf(var + kEps);
  }
  __syncthreads();
  if (threadIdx.x < kCPG) {
    int c = g * kCPG + threadIdx.x;
    float sc = gamma[c] * sR;
    float sh = beta[c] - sM * sc;
    if (t == 0) { scaleX[b * kC + c] = sc; shiftX[b * kC + c] = sh; }
    else        { scaleY[b * kC + c] = sc; shiftY[b * kC + c] = sh; }
  }
}

// ---------------------------------------------------------------------------
// Kernel 2: QKV conv1x1 via plain bf16 MFMA (unchanged from round 7).
// ---------------------------------------------------------------------------
__global__ __launch_bounds__(256, 2)
void qkv_mfma_kernel(const float* __restrict__ x, const float* __restrict__ y,
                     const float* __restrict__ wq, const float* __restrict__ bq,
                     const float* __restrict__ wk, const float* __restrict__ bk,
                     const float* __restrict__ wv, const float* __restrict__ bv,
                     const float* __restrict__ scaleX, const float* __restrict__ shiftX,
                     const float* __restrict__ scaleY, const float* __restrict__ shiftY,
                     unsigned short* __restrict__ Qo, unsigned short* __restrict__ Ko,
                     unsigned short* __restrict__ Vo) {
  int z  = blockIdx.y;                 // 0=q (from x), 1=k, 2=v (from y)
  int bi = blockIdx.x;
  int pt = bi & 63;
  int b  = bi >> 6;
  int pbase = pt * 64;
  const float* X    = (z == 0 ? x : y) + (size_t)b * kC * kHW;
  const float* W    = (z == 0 ? wq : (z == 1 ? wk : wv));
  const float* bias = (z == 0 ? bq : (z == 1 ? bk : bv));
  const float* SC   = (z == 0 ? scaleX : scaleY) + b * kC;
  const float* SH   = (z == 0 ? shiftX : shiftY) + b * kC;

  __shared__ short Ws[256][40];   // [o][c] +8 pad
  __shared__ short Xs[64][40];    // [p][c] +8 pad
  __shared__ float Xt[32][68];    // fp32 transpose staging [c][p]

  int tid  = threadIdx.x;
  int lane = tid & 63;
  int w    = tid >> 6;
  int lrow = lane & 15;
  int lgrp = lane >> 4;

  f32x4 acc[4][4];
  #pragma unroll
  for (int i = 0; i < 4; ++i)
    #pragma unroll
    for (int j = 0; j < 4; ++j) acc[i][j] = (f32x4){0.f, 0.f, 0.f, 0.f};

  for (int c0 = 0; c0 < kC; c0 += 32) {
    __syncthreads();
    {  // ---- stage W row o=tid, 32 c ----
      const float* s = W + (size_t)tid * kC + c0;
      #pragma unroll
      for (int seg = 0; seg < 4; ++seg) {
        float4 a0 = *(const float4*)(s + seg * 8);
        float4 a1 = *(const float4*)(s + seg * 8 + 4);
        float v[8] = {a0.x, a0.y, a0.z, a0.w, a1.x, a1.y, a1.z, a1.w};
        short hh[8];
        #pragma unroll
        for (int i = 0; i < 8; ++i) hh[i] = (short)f2bf(v[i]);
        *(bf16x8*)&Ws[tid][seg * 8] = *(bf16x8*)hh;
      }
    }
    {  // ---- stage X [32c][64p] normalized fp32 ----
      int c  = tid >> 3;
      int p8 = (tid & 7) * 8;
      const float* s = X + (size_t)(c0 + c) * kHW + pbase + p8;
      float sc = SC[c0 + c], sh = SH[c0 + c];
      float4 a0 = *(const float4*)(s);
      float4 a1 = *(const float4*)(s + 4);
      float4 r0 = make_float4(fmaf(a0.x, sc, sh), fmaf(a0.y, sc, sh), fmaf(a0.z, sc, sh), fmaf(a0.w, sc, sh));
      float4 r1 = make_float4(fmaf(a1.x, sc, sh), fmaf(a1.y, sc, sh), fmaf(a1.z, sc, sh), fmaf(a1.w, sc, sh));
      *(float4*)&Xt[c][p8]     = r0;
      *(float4*)&Xt[c][p8 + 4] = r1;
    }
    __syncthreads();
    {  // ---- transpose Xt -> Xs[p][c] ----
      int p  = tid & 63;
      int cs = (tid >> 6) * 8;
      short hh[8];
      #pragma unroll
      for (int i = 0; i < 8; ++i) hh[i] = (short)f2bf(Xt[cs + i][p]);
      *(bf16x8*)&Xs[p][cs] = *(bf16x8*)hh;
    }
    __syncthreads();

    if (z < 2) {
      bf16x8 am[4], bn[4];
      #pragma unroll
      for (int mt = 0; mt < 4; ++mt)
        am[mt] = *(const bf16x8*)&Ws[w * 64 + mt * 16 + lrow][lgrp * 8];
      #pragma unroll
      for (int nt = 0; nt < 4; ++nt)
        bn[nt] = *(const bf16x8*)&Xs[nt * 16 + lrow][lgrp * 8];
      #pragma unroll
      for (int mt = 0; mt < 4; ++mt)
        #pragma unroll
        for (int nt = 0; nt < 4; ++nt)
          acc[mt][nt] = MFMA16(am[mt], bn[nt], acc[mt][nt]);
    } else {
      bf16x8 am[4], bn[4];
      #pragma unroll
      for (int mt = 0; mt < 4; ++mt)
        am[mt] = *(const bf16x8*)&Xs[mt * 16 + lrow][lgrp * 8];
      #pragma unroll
      for (int nt = 0; nt < 4; ++nt)
        bn[nt] = *(const bf16x8*)&Ws[w * 64 + nt * 16 + lrow][lgrp * 8];
      #pragma unroll
      for (int mt = 0; mt < 4; ++mt)
        #pragma unroll
        for (int nt = 0; nt < 4; ++nt)
          acc[mt][nt] = MFMA16(am[mt], bn[nt], acc[mt][nt]);
    }
  }

  // ---- epilogue ----
  if (z < 2) {
    float osc = (z == 0) ? 0.0625f : 1.0f;
    unsigned short* T = ((z == 0) ? Qo : Ko) + (size_t)b * kHW * kC;
    #pragma unroll
    for (int mt = 0; mt < 4; ++mt) {
      int o0 = w * 64 + mt * 16 + lgrp * 4;
      float4 b4 = *(const float4*)&bias[o0];
      #pragma unroll
      for (int nt = 0; nt < 4; ++nt) {
        int p = pbase + nt * 16 + lrow;
        ushort4 hh;
        hh.x = f2bf((acc[mt][nt][0] + b4.x) * osc);
        hh.y = f2bf((acc[mt][nt][1] + b4.y) * osc);
        hh.z = f2bf((acc[mt][nt][2] + b4.z) * osc);
        hh.w = f2bf((acc[mt][nt][3] + b4.w) * osc);
        *(ushort4*)&T[(size_t)p * kC + o0] = hh;
      }
    }
  } else {
    unsigned short* Vb = Vo + (size_t)b * kHW * kC;   // [o][p]
    #pragma unroll
    for (int nt = 0; nt < 4; ++nt) {
      int o = w * 64 + nt * 16 + lrow;
      float bo = bias[o];
      #pragma unroll
      for (int mt = 0; mt < 4; ++mt) {
        int p0 = pbase + mt * 16 + lgrp * 4;
        ushort4 hh;
        hh.x = f2bf(acc[mt][nt][0] + bo);
        hh.y = f2bf(acc[mt][nt][1] + bo);
        hh.z = f2bf(acc[mt][nt][2] + bo);
        hh.w = f2bf(acc[mt][nt][3] + bo);
        *(ushort4*)&Vb[(size_t)o * kHW + p0] = hh;
      }
    }
  }
}

// ---------------------------------------------------------------------------
// Kernel 3: flash attention on 32x32x16 MFMA.
//   Block = 128 queries, 4 waves x 32q. Grid 256 (1 block/CU; b = bid&7 -> XCD).
//   Per kt (32 keys): prefetch next K/V to regs -> QK^T (16 MFMA, one f32x16)
//   -> softmax (16 rows/lane, 32-lane shfl reduce) -> P via wave-private LDS
//   -> PV (16 MFMA) -> ds_write next tile into buf^1 -> ONE barrier.
// ---------------------------------------------------------------------------
__global__ __launch_bounds__(256, 1)
void flash_mfma_kernel(const unsigned short* __restrict__ Q,
                       const unsigned short* __restrict__ K,
                       const unsigned short* __restrict__ V,
                       float* __restrict__ Ot) {
  int bid = blockIdx.x;
  int b  = bid & 7;                 // one batch per XCD: K/V stay L2-resident
  int qt = bid >> 3;                // 0..31
  const size_t toff = (size_t)b * kHW * kC;
  const unsigned short* Qb = Q + toff;   // [q][c]
  const unsigned short* Kb = K + toff;   // [k][c]
  const unsigned short* Vb = V + toff;   // [c][k]
  float* O = Ot + toff;                  // [q][c]

  __shared__ short K_s[2][32][264];   // [key][c] +8 pad  (16.9 KB x2)
  __shared__ short V_s[2][256][40];   // [c][key] +8 pad  (20.5 KB x2)
  __shared__ short P_s[4][32][40];    // per-wave [q][key] +8 pad (10.2 KB)

  int tid  = threadIdx.x;
  int lane = tid & 63;
  int w    = tid >> 6;
  int l31  = lane & 31;
  int hi   = lane >> 5;

  // ---- Q fragments (32x32 A-frags): row = l31, k-slice = hi*8; 16 c-steps ----
  bf16x8 qf[16];
  {
    int qrow = qt * 128 + w * 32 + l31;
    const unsigned short* qp = Qb + (size_t)qrow * kC + hi * 8;
    #pragma unroll
    for (int cc = 0; cc < 16; ++cc) qf[cc] = *(const bf16x8*)(qp + cc * 16);
  }

  // staging geometry (per thread: 4x16B of K, 4x16B of V)
  int krow0 = tid >> 5;              // 0..7
  int kcol  = (tid & 31) * 8;
  int vc0   = tid >> 2;              // 0..63
  int vpart = (tid & 3) * 8;

  {  // prologue: stage tile 0 into buffer 0
    #pragma unroll
    for (int rep = 0; rep < 4; ++rep) {
      *(int4*)&K_s[0][krow0 + rep * 8][kcol] =
          *(const int4*)(Kb + (size_t)(krow0 + rep * 8) * kC + kcol);
      *(int4*)&V_s[0][vc0 + rep * 64][vpart] =
          *(const int4*)(Vb + (size_t)(vc0 + rep * 64) * kHW + vpart);
    }
  }
  __syncthreads();

  f32x16 accO[8];
  #pragma unroll
  for (int ct = 0; ct < 8; ++ct)
    #pragma unroll
    for (int r = 0; r < 16; ++r) accO[ct][r] = 0.f;
  float m_[16], l_[16];
  #pragma unroll
  for (int r = 0; r < 16; ++r) { m_[r] = -1e30f; l_[r] = 0.f; }

  int cur = 0;
  for (int kt = 0; kt < 128; ++kt) {
    // ---- prefetch next tile into registers (hidden under MFMA phases) ----
    int4 gK[4], gV[4];
    if (kt < 127) {
      int kb2 = (kt + 1) * 32;
      #pragma unroll
      for (int rep = 0; rep < 4; ++rep) {
        gK[rep] = *(const int4*)(Kb + (size_t)(kb2 + krow0 + rep * 8) * kC + kcol);
        gV[rep] = *(const int4*)(Vb + (size_t)(vc0 + rep * 64) * kHW + kb2 + vpart);
      }
    }

    // ---- QK^T: S[32q x 32k] per wave, 16 MFMA over 256 c ----
    f32x16 S;
    #pragma unroll
    for (int r = 0; r < 16; ++r) S[r] = 0.f;
    #pragma unroll
    for (int cc = 0; cc < 16; ++cc) {
      bf16x8 kf = *(const bf16x8*)&K_s[cur][l31][cc * 16 + hi * 8];
      S = MFMA32(qf[cc], kf, S);
    }

    // ---- online softmax: 16 rows/lane; reduce over the 32-lane half ----
    #pragma unroll
    for (int r = 0; r < 16; ++r) {
      float mx = S[r];
      mx = fmaxf(mx, __shfl_xor(mx, 1));
      mx = fmaxf(mx, __shfl_xor(mx, 2));
      mx = fmaxf(mx, __shfl_xor(mx, 4));
      mx = fmaxf(mx, __shfl_xor(mx, 8));
      mx = fmaxf(mx, __shfl_xor(mx, 16));
      float mn = fmaxf(m_[r], mx);
      float fr = __expf(m_[r] - mn);
      unsigned short u = f2bf(__expf(S[r] - mn));
      float sum = bf2f(u);
      sum += __shfl_xor(sum, 1);
      sum += __shfl_xor(sum, 2);
      sum += __shfl_xor(sum, 4);
      sum += __shfl_xor(sum, 8);
      sum += __shfl_xor(sum, 16);
      l_[r] = l_[r] * fr + sum;
      m_[r] = mn;
      int crow = (r & 3) + 8 * (r >> 2) + 4 * hi;
      P_s[w][crow][l31] = (short)u;          // banks: 2 lanes/bank, free
      #pragma unroll
      for (int ct = 0; ct < 8; ++ct) accO[ct][r] *= fr;
    }

    // ---- PV: O[32q x 256c] += P[32q x 32k] * V[32k x 256c] ----
    // A-frag: row=l31, keys hi*8 (+16 for second MFMA); in-wave write->read
    bf16x8 pa0 = *(const bf16x8*)&P_s[w][l31][hi * 8];
    bf16x8 pa1 = *(const bf16x8*)&P_s[w][l31][16 + hi * 8];
    #pragma unroll
    for (int ct = 0; ct < 8; ++ct) {
      bf16x8 v0 = *(const bf16x8*)&V_s[cur][ct * 32 + l31][hi * 8];
      bf16x8 v1 = *(const bf16x8*)&V_s[cur][ct * 32 + l31][16 + hi * 8];
      accO[ct] = MFMA32(pa0, v0, accO[ct]);
      accO[ct] = MFMA32(pa1, v1, accO[ct]);
    }

    // ---- write next tile into the other buffer; single barrier ----
    if (kt < 127) {
      #pragma unroll
      for (int rep = 0; rep < 4; ++rep) {
        *(int4*)&K_s[cur ^ 1][krow0 + rep * 8][kcol] = gK[rep];
        *(int4*)&V_s[cur ^ 1][vc0 + rep * 64][vpart] = gV[rep];
      }
    }
    __syncthreads();
    cur ^= 1;
  }

  // ---- epilogue: normalize, write O [q][c] fp32 ----
  int q0 = qt * 128 + w * 32;
  #pragma unroll
  for (int r = 0; r < 16; ++r) {
    float inv = 1.0f / l_[r];
    int q = q0 + (r & 3) + 8 * (r >> 2) + 4 * hi;
    float* orow = O + (size_t)q * kC + l31;
    #pragma unroll
    for (int ct = 0; ct < 8; ++ct) {
      orow[ct * 32] = accO[ct][r] * inv;
    }
  }
}

// ---------------------------------------------------------------------------
// Kernel 4: proj conv1x1 + residual via bf16 MFMA, hi/lo 3-term (fp32 output).
// ---------------------------------------------------------------------------
__global__ __launch_bounds__(256, 2)
void proj_mfma_kernel(const float* __restrict__ Ot, const float* __restrict__ wp,
                      const float* __restrict__ bp, const float* __restrict__ x,
                      float* __restrict__ out) {
  int bi = blockIdx.x;
  int pt = bi & 63;
  int b  = bi >> 6;
  int pbase = pt * 64;
  const float* Ob = Ot + (size_t)b * kHW * kC;   // [p][c]

  __shared__ short Ws_h[256][40];   // [o][c]
  __shared__ short Ws_l[256][40];
  __shared__ short Os_h[64][40];    // [p][c]
  __shared__ short Os_l[64][40];

  int tid  = threadIdx.x;
  int lane = tid & 63;
  int w    = tid >> 6;
  int lrow = lane & 15;
  int lgrp = lane >> 4;

  f32x4 acc[4][4];
  #pragma unroll
  for (int i = 0; i < 4; ++i)
    #pragma unroll
    for (int j = 0; j < 4; ++j) acc[i][j] = (f32x4){0.f, 0.f, 0.f, 0.f};

  for (int c0 = 0; c0 < kC; c0 += 32) {
    __syncthreads();
    {  // stage Wp row o=tid
      const float* s = wp + (size_t)tid * kC + c0;
      #pragma unroll
      for (int seg = 0; seg < 4; ++seg) {
        float4 a0 = *(const float4*)(s + seg * 8);
        float4 a1 = *(const float4*)(s + seg * 8 + 4);
        float v[8] = {a0.x, a0.y, a0.z, a0.w, a1.x, a1.y, a1.z, a1.w};
        short hh[8], ll[8];
        #pragma unroll
        for (int i = 0; i < 8; ++i) {
          unsigned short h = f2bf(v[i]);
          hh[i] = (short)h;
          ll[i] = (short)f2bf(v[i] - bf2f(h));
        }
        *(bf16x8*)&Ws_h[tid][seg * 8] = *(bf16x8*)hh;
        *(bf16x8*)&Ws_l[tid][seg * 8] = *(bf16x8*)ll;
      }
    }
    {  // stage O tile [64p][32c] hi/lo (Ot already [p][c])
      int p  = tid >> 2;
      int c8 = (tid & 3) * 8;
      const float* s = Ob + (size_t)(pbase + p) * kC + c0 + c8;
      float4 a0 = *(const float4*)(s);
      float4 a1 = *(const float4*)(s + 4);
      float v[8] = {a0.x, a0.y, a0.z, a0.w, a1.x, a1.y, a1.z, a1.w};
      short hh[8], ll[8];
      #pragma unroll
      for (int i = 0; i < 8; ++i) {
        unsigned short h = f2bf(v[i]);
        hh[i] = (short)h;
        ll[i] = (short)f2bf(v[i] - bf2f(h));
      }
      *(bf16x8*)&Os_h[p][c8] = *(bf16x8*)hh;
      *(bf16x8*)&Os_l[p][c8] = *(bf16x8*)ll;
    }
    __syncthreads();

    bf16x8 ah[4], al[4], bh[4], bl[4];
    #pragma unroll
    for (int mt = 0; mt < 4; ++mt) {
      ah[mt] = *(const bf16x8*)&Os_h[mt * 16 + lrow][lgrp * 8];
      al[mt] = *(const bf16x8*)&Os_l[mt * 16 + lrow][lgrp * 8];
    }
    #pragma unroll
    for (int nt = 0; nt < 4; ++nt) {
      bh[nt] = *(const bf16x8*)&Ws_h[w * 64 + nt * 16 + lrow][lgrp * 8];
      bl[nt] = *(const bf16x8*)&Ws_l[w * 64 + nt * 16 + lrow][lgrp * 8];
    }
    #pragma unroll
    for (int mt = 0; mt < 4; ++mt)
      #pragma unroll
      for (int nt = 0; nt < 4; ++nt) {
        acc[mt][nt] = MFMA16(ah[mt], bh[nt], acc[mt][nt]);
        acc[mt][nt] = MFMA16(al[mt], bh[nt], acc[mt][nt]);
        acc[mt][nt] = MFMA16(ah[mt], bl[nt], acc[mt][nt]);
      }
  }

  // epilogue: out[b][o][p] = acc + bp[o] + x[b][o][p]
  #pragma unroll
  for (int nt = 0; nt < 4; ++nt) {
    int o = w * 64 + nt * 16 + lrow;
    float bo = bp[o];
    #pragma unroll
    for (int mt = 0; mt < 4; ++mt) {
      int p0 = pbase + mt * 16 + lgrp * 4;
      const float* xr   = x   + ((size_t)b * kC + o) * kHW + p0;
      float*       orow = out + ((size_t)b * kC + o) * kHW + p0;
      float4 xv = *(const float4*)xr;
      float4 v = make_float4(acc[mt][nt][0] + bo + xv.x, acc[mt][nt][1] + bo + xv.y,
                             acc[mt][nt][2] + bo + xv.z, acc[mt][nt][3] + bo + xv.w);
      *(float4*)orow = v;
    }
  }
}

// ---------------------------------------------------------------------------
extern "C" void kernel_launch(void* const* d_in, const int* in_sizes, int n_in,
                              void* d_out, int out_size, void* d_ws, size_t ws_size,
                              hipStream_t stream) {
  (void)in_sizes; (void)n_in; (void)out_size;
  const float* x     = (const float*)d_in[0];
  const float* y     = (const float*)d_in[1];
  const float* gamma = (const float*)d_in[2];
  const float* beta  = (const float*)d_in[3];
  const float* wq    = (const float*)d_in[4];
  const float* bq    = (const float*)d_in[5];
  const float* wk    = (const float*)d_in[6];
  const float* bk    = (const float*)d_in[7];
  const float* wv    = (const float*)d_in[8];
  const float* bv    = (const float*)d_in[9];
  const float* wp    = (const float*)d_in[10];
  const float* bp    = (const float*)d_in[11];
  float* out = (float*)d_out;

  char* ws = (char*)d_ws;
  size_t bsz = (size_t)kB * kHW * kC * sizeof(unsigned short);  // 16 MB bf16 tensor
  size_t fsz = (size_t)kB * kHW * kC * sizeof(float);           // 32 MB fp32 tensor
  size_t need = 3 * bsz + fsz + 4 * (size_t)kB * kC * sizeof(float);
  if (ws_size < need) return;

  unsigned short* Qb = (unsigned short*)(ws);
  unsigned short* Kb = (unsigned short*)(ws + 1 * bsz);
  unsigned short* Vb = (unsigned short*)(ws + 2 * bsz);
  float* Ot     = (float*)(ws + 3 * bsz);
  float* scaleX = (float*)(ws + 3 * bsz + fsz);
  float* shiftX = scaleX + kB * kC;
  float* scaleY = shiftX + kB * kC;
  float* shiftY = scaleY + kB * kC;

  gn_stats_kernel<<<dim3(64), dim3(256), 0, stream>>>(
      x, y, gamma, beta, scaleX, shiftX, scaleY, shiftY);
  qkv_mfma_kernel<<<dim3(kB * 64, 3), dim3(256), 0, stream>>>(
      x, y, wq, bq, wk, bk, wv, bv, scaleX, shiftX, scaleY, shiftY,
      Qb, Kb, Vb);
  flash_mfma_kernel<<<dim3(256), dim3(256), 0, stream>>>(Qb, Kb, Vb, Ot);
  proj_mfma_kernel<<<dim3(kB * 64), dim3(256), 0, stream>>>(Ot, wp, bp, x, out);
}

// Round 9
// 599.674 us; speedup vs baseline: 2.0573x; 2.0573x over previous
//
#include <hip/hip_runtime.h>
#include <math.h>

// AttnBlock fused pipeline, round 9: r7 skeleton with KVBLK widened 32 -> 64.
// r5 vs r7 showed flash is serial-structure-bound (barriers + staging latency +
// softmax chain per iteration), not MFMA/LDS-throughput-bound -> halve the
// iteration count, keep everything else identical.
//   x,y: [8, 256, 64, 64] fp32; GN groups=4 eps=1e-6; 4 conv1x1 weights [256,256].
// Fragment convention (HW-validated r3/r5/r7):
//   A-frag: m = lane&15, k-slice = (lane>>4)*8 ; B-frag: n = lane&15, same k
//   D: col = lane&15, row = (lane>>4)*4 + reg.
// Workspace: Q,K (bf16 [p][c]), V (bf16 [c][p]) 16MB each + Ot (fp32 32MB) + stats.

namespace {
constexpr int kB   = 8;
constexpr int kC   = 256;
constexpr int kCPG = 64;
constexpr int kHW  = 4096;
constexpr float kEps = 1e-6f;
}

typedef short bf16x8 __attribute__((ext_vector_type(8)));   // 8 bf16 in 4 VGPRs
typedef float f32x4  __attribute__((ext_vector_type(4)));

#define MFMA16(a, b, c) __builtin_amdgcn_mfma_f32_16x16x32_bf16((a), (b), (c), 0, 0, 0)

__device__ __forceinline__ unsigned short f2bf(float v) {   // RNE fp32 -> bf16 bits
  unsigned u = __float_as_uint(v);
  u += 0x7FFFu + ((u >> 16) & 1u);
  return (unsigned short)(u >> 16);
}
__device__ __forceinline__ float bf2f(unsigned short h) {
  return __uint_as_float(((unsigned)h) << 16);
}

// ---------------------------------------------------------------------------
// Kernel 1: GroupNorm statistics -> per-(tensor,b,c) scale/shift (unchanged)
// ---------------------------------------------------------------------------
__global__ __launch_bounds__(256)
void gn_stats_kernel(const float* __restrict__ x, const float* __restrict__ y,
                     const float* __restrict__ gamma, const float* __restrict__ beta,
                     float* __restrict__ scaleX, float* __restrict__ shiftX,
                     float* __restrict__ scaleY, float* __restrict__ shiftY) {
  int blk = blockIdx.x;            // t*32 + b*4 + g
  int g = blk & 3;
  int b = (blk >> 2) & 7;
  int t = blk >> 5;
  const float* src = (t == 0 ? x : y) + ((size_t)b * kC + (size_t)g * kCPG) * kHW;
  const int N = kCPG * kHW;
  float sum = 0.f, ssq = 0.f;
  for (int i = threadIdx.x * 4; i < N; i += 256 * 4) {
    float4 v = *(const float4*)(src + i);
    sum += v.x + v.y + v.z + v.w;
    ssq += v.x * v.x + v.y * v.y + v.z * v.z + v.w * v.w;
  }
  #pragma unroll
  for (int off = 32; off > 0; off >>= 1) {
    sum += __shfl_down(sum, off);
    ssq += __shfl_down(ssq, off);
  }
  __shared__ float rs[4], rq[4];
  __shared__ float sM, sR;
  int lane = threadIdx.x & 63, w = threadIdx.x >> 6;
  if (lane == 0) { rs[w] = sum; rq[w] = ssq; }
  __syncthreads();
  if (threadIdx.x == 0) {
    float s = rs[0] + rs[1] + rs[2] + rs[3];
    float q = rq[0] + rq[1] + rq[2] + rq[3];
    float mean = s / (float)N;
    float var  = q / (float)N - mean * mean;
    sM = mean;
    sR = rsqrtf(var + kEps);
  }
  __syncthreads();
  if (threadIdx.x < kCPG) {
    int c = g * kCPG + threadIdx.x;
    float sc = gamma[c] * sR;
    float sh = beta[c] - sM * sc;
    if (t == 0) { scaleX[b * kC + c] = sc; shiftX[b * kC + c] = sh; }
    else        { scaleY[b * kC + c] = sc; shiftY[b * kC + c] = sh; }
  }
}

// ---------------------------------------------------------------------------
// Kernel 2: QKV conv1x1 via plain bf16 MFMA (unchanged from round 7).
// ---------------------------------------------------------------------------
__global__ __launch_bounds__(256, 2)
void qkv_mfma_kernel(const float* __restrict__ x, const float* __restrict__ y,
                     const float* __restrict__ wq, const float* __restrict__ bq,
                     const float* __restrict__ wk, const float* __restrict__ bk,
                     const float* __restrict__ wv, const float* __restrict__ bv,
                     const float* __restrict__ scaleX, const float* __restrict__ shiftX,
                     const float* __restrict__ scaleY, const float* __restrict__ shiftY,
                     unsigned short* __restrict__ Qo, unsigned short* __restrict__ Ko,
                     unsigned short* __restrict__ Vo) {
  int z  = blockIdx.y;                 // 0=q (from x), 1=k, 2=v (from y)
  int bi = blockIdx.x;
  int pt = bi & 63;
  int b  = bi >> 6;
  int pbase = pt * 64;
  const float* X    = (z == 0 ? x : y) + (size_t)b * kC * kHW;
  const float* W    = (z == 0 ? wq : (z == 1 ? wk : wv));
  const float* bias = (z == 0 ? bq : (z == 1 ? bk : bv));
  const float* SC   = (z == 0 ? scaleX : scaleY) + b * kC;
  const float* SH   = (z == 0 ? shiftX : shiftY) + b * kC;

  __shared__ short Ws[256][40];   // [o][c] +8 pad
  __shared__ short Xs[64][40];    // [p][c] +8 pad
  __shared__ float Xt[32][68];    // fp32 transpose staging [c][p]

  int tid  = threadIdx.x;
  int lane = tid & 63;
  int w    = tid >> 6;
  int lrow = lane & 15;
  int lgrp = lane >> 4;

  f32x4 acc[4][4];
  #pragma unroll
  for (int i = 0; i < 4; ++i)
    #pragma unroll
    for (int j = 0; j < 4; ++j) acc[i][j] = (f32x4){0.f, 0.f, 0.f, 0.f};

  for (int c0 = 0; c0 < kC; c0 += 32) {
    __syncthreads();
    {  // ---- stage W row o=tid, 32 c ----
      const float* s = W + (size_t)tid * kC + c0;
      #pragma unroll
      for (int seg = 0; seg < 4; ++seg) {
        float4 a0 = *(const float4*)(s + seg * 8);
        float4 a1 = *(const float4*)(s + seg * 8 + 4);
        float v[8] = {a0.x, a0.y, a0.z, a0.w, a1.x, a1.y, a1.z, a1.w};
        short hh[8];
        #pragma unroll
        for (int i = 0; i < 8; ++i) hh[i] = (short)f2bf(v[i]);
        *(bf16x8*)&Ws[tid][seg * 8] = *(bf16x8*)hh;
      }
    }
    {  // ---- stage X [32c][64p] normalized fp32 ----
      int c  = tid >> 3;
      int p8 = (tid & 7) * 8;
      const float* s = X + (size_t)(c0 + c) * kHW + pbase + p8;
      float sc = SC[c0 + c], sh = SH[c0 + c];
      float4 a0 = *(const float4*)(s);
      float4 a1 = *(const float4*)(s + 4);
      float4 r0 = make_float4(fmaf(a0.x, sc, sh), fmaf(a0.y, sc, sh), fmaf(a0.z, sc, sh), fmaf(a0.w, sc, sh));
      float4 r1 = make_float4(fmaf(a1.x, sc, sh), fmaf(a1.y, sc, sh), fmaf(a1.z, sc, sh), fmaf(a1.w, sc, sh));
      *(float4*)&Xt[c][p8]     = r0;
      *(float4*)&Xt[c][p8 + 4] = r1;
    }
    __syncthreads();
    {  // ---- transpose Xt -> Xs[p][c] ----
      int p  = tid & 63;
      int cs = (tid >> 6) * 8;
      short hh[8];
      #pragma unroll
      for (int i = 0; i < 8; ++i) hh[i] = (short)f2bf(Xt[cs + i][p]);
      *(bf16x8*)&Xs[p][cs] = *(bf16x8*)hh;
    }
    __syncthreads();

    if (z < 2) {
      bf16x8 am[4], bn[4];
      #pragma unroll
      for (int mt = 0; mt < 4; ++mt)
        am[mt] = *(const bf16x8*)&Ws[w * 64 + mt * 16 + lrow][lgrp * 8];
      #pragma unroll
      for (int nt = 0; nt < 4; ++nt)
        bn[nt] = *(const bf16x8*)&Xs[nt * 16 + lrow][lgrp * 8];
      #pragma unroll
      for (int mt = 0; mt < 4; ++mt)
        #pragma unroll
        for (int nt = 0; nt < 4; ++nt)
          acc[mt][nt] = MFMA16(am[mt], bn[nt], acc[mt][nt]);
    } else {
      bf16x8 am[4], bn[4];
      #pragma unroll
      for (int mt = 0; mt < 4; ++mt)
        am[mt] = *(const bf16x8*)&Xs[mt * 16 + lrow][lgrp * 8];
      #pragma unroll
      for (int nt = 0; nt < 4; ++nt)
        bn[nt] = *(const bf16x8*)&Ws[w * 64 + nt * 16 + lrow][lgrp * 8];
      #pragma unroll
      for (int mt = 0; mt < 4; ++mt)
        #pragma unroll
        for (int nt = 0; nt < 4; ++nt)
          acc[mt][nt] = MFMA16(am[mt], bn[nt], acc[mt][nt]);
    }
  }

  // ---- epilogue ----
  if (z < 2) {
    float osc = (z == 0) ? 0.0625f : 1.0f;
    unsigned short* T = ((z == 0) ? Qo : Ko) + (size_t)b * kHW * kC;
    #pragma unroll
    for (int mt = 0; mt < 4; ++mt) {
      int o0 = w * 64 + mt * 16 + lgrp * 4;
      float4 b4 = *(const float4*)&bias[o0];
      #pragma unroll
      for (int nt = 0; nt < 4; ++nt) {
        int p = pbase + nt * 16 + lrow;
        ushort4 hh;
        hh.x = f2bf((acc[mt][nt][0] + b4.x) * osc);
        hh.y = f2bf((acc[mt][nt][1] + b4.y) * osc);
        hh.z = f2bf((acc[mt][nt][2] + b4.z) * osc);
        hh.w = f2bf((acc[mt][nt][3] + b4.w) * osc);
        *(ushort4*)&T[(size_t)p * kC + o0] = hh;
      }
    }
  } else {
    unsigned short* Vb = Vo + (size_t)b * kHW * kC;   // [o][p]
    #pragma unroll
    for (int nt = 0; nt < 4; ++nt) {
      int o = w * 64 + nt * 16 + lrow;
      float bo = bias[o];
      #pragma unroll
      for (int mt = 0; mt < 4; ++mt) {
        int p0 = pbase + mt * 16 + lgrp * 4;
        ushort4 hh;
        hh.x = f2bf(acc[mt][nt][0] + bo);
        hh.y = f2bf(acc[mt][nt][1] + bo);
        hh.z = f2bf(acc[mt][nt][2] + bo);
        hh.w = f2bf(acc[mt][nt][3] + bo);
        *(ushort4*)&Vb[(size_t)o * kHW + p0] = hh;
      }
    }
  }
}

// ---------------------------------------------------------------------------
// Kernel 3: MFMA flash attention, r7 skeleton, KVBLK = 64.
//   Per 64-key iter: barrier -> stage K[64][256]/V[256][64] -> barrier ->
//   QK^T (32 MFMA) -> ONE softmax pass (4 rows, 4+4 shfl over 4-wide locals)
//   -> P_s (wave-private) -> PV (32 MFMA).  LDS 78 KB -> 2 blocks/CU.
// ---------------------------------------------------------------------------
__global__ __launch_bounds__(256, 2)
void flash_mfma_kernel(const unsigned short* __restrict__ Q,
                       const unsigned short* __restrict__ K,
                       const unsigned short* __restrict__ V,
                       float* __restrict__ Ot) {
  int bid = blockIdx.x;
  int b  = bid & 7;                 // one batch per XCD: K/V stay L2-resident
  int qt = bid >> 3;
  const size_t toff = (size_t)b * kHW * kC;
  const unsigned short* Qb = Q + toff;   // [q][c]
  const unsigned short* Kb = K + toff;   // [k][c]
  const unsigned short* Vb = V + toff;   // [c][k]
  float* O = Ot + toff;                  // [q][c]

  __shared__ short K_s[64][264];   // [key][c] +8 pad   (33.8 KB)
  __shared__ short V_s[256][72];   // [c][key] +8 pad   (36.9 KB)
  __shared__ short P_s[64][72];    // [q][key] +8 pad   (9.2 KB, wave-private)

  int tid  = threadIdx.x;
  int lane = tid & 63;
  int w    = tid >> 6;
  int lrow = lane & 15;
  int lgrp = lane >> 4;

  // ---- Q fragments in registers (A-frags), loaded once ----
  bf16x8 qf[8];
  {
    int qrow = qt * 64 + w * 16 + lrow;
    const unsigned short* qb = Qb + (size_t)qrow * kC + lgrp * 8;
    #pragma unroll
    for (int cc = 0; cc < 8; ++cc) qf[cc] = *(const bf16x8*)(qb + cc * 32);
  }

  // staging geometry: K 8 int4/thread, V 8 int4/thread
  int krow0 = tid >> 5;              // 0..7  (+rep*8 -> 64 rows)
  int kcol  = (tid & 31) * 8;
  int vc0   = tid >> 3;              // 0..31 (+rep*32 -> 256 rows)
  int vpart = (tid & 7) * 8;         // 8 granules per 64-key row

  f32x4 accO[16];
  #pragma unroll
  for (int nt = 0; nt < 16; ++nt) accO[nt] = (f32x4){0.f, 0.f, 0.f, 0.f};
  float m_[4], l_[4];
  #pragma unroll
  for (int r = 0; r < 4; ++r) { m_[r] = -1e30f; l_[r] = 0.f; }

  for (int kt = 0; kt < 64; ++kt) {
    int kbase = kt * 64;
    __syncthreads();   // previous iteration done reading K_s/V_s
    #pragma unroll
    for (int rep = 0; rep < 8; ++rep) {
      *(int4*)&K_s[krow0 + rep * 8][kcol] =
          *(const int4*)(Kb + (size_t)(kbase + krow0 + rep * 8) * kC + kcol);
      *(int4*)&V_s[vc0 + rep * 32][vpart] =
          *(const int4*)(Vb + (size_t)(vc0 + rep * 32) * kHW + kbase + vpart);
    }
    __syncthreads();

    // ---- QK^T: S[16q x 64k] per wave, four 16-key n-tiles ----
    f32x4 s0 = (f32x4){0.f, 0.f, 0.f, 0.f};
    f32x4 s1 = (f32x4){0.f, 0.f, 0.f, 0.f};
    f32x4 s2 = (f32x4){0.f, 0.f, 0.f, 0.f};
    f32x4 s3 = (f32x4){0.f, 0.f, 0.f, 0.f};
    #pragma unroll
    for (int cc = 0; cc < 8; ++cc) {
      int coff = cc * 32 + lgrp * 8;
      bf16x8 k0 = *(const bf16x8*)&K_s[lrow][coff];
      bf16x8 k1 = *(const bf16x8*)&K_s[16 + lrow][coff];
      bf16x8 k2 = *(const bf16x8*)&K_s[32 + lrow][coff];
      bf16x8 k3 = *(const bf16x8*)&K_s[48 + lrow][coff];
      s0 = MFMA16(qf[cc], k0, s0);
      s1 = MFMA16(qf[cc], k1, s1);
      s2 = MFMA16(qf[cc], k2, s2);
      s3 = MFMA16(qf[cc], k3, s3);
    }

    // ---- online softmax: one pass per 64 keys ----
    int prow = w * 16 + lgrp * 4;
    #pragma unroll
    for (int r = 0; r < 4; ++r) {
      float mx = fmaxf(fmaxf(s0[r], s1[r]), fmaxf(s2[r], s3[r]));
      mx = fmaxf(mx, __shfl_xor(mx, 1));
      mx = fmaxf(mx, __shfl_xor(mx, 2));
      mx = fmaxf(mx, __shfl_xor(mx, 4));
      mx = fmaxf(mx, __shfl_xor(mx, 8));
      float mn = fmaxf(m_[r], mx);
      float f  = __expf(m_[r] - mn);
      unsigned short u0 = f2bf(__expf(s0[r] - mn));
      unsigned short u1 = f2bf(__expf(s1[r] - mn));
      unsigned short u2 = f2bf(__expf(s2[r] - mn));
      unsigned short u3 = f2bf(__expf(s3[r] - mn));
      float sum = (bf2f(u0) + bf2f(u1)) + (bf2f(u2) + bf2f(u3));
      sum += __shfl_xor(sum, 1);
      sum += __shfl_xor(sum, 2);
      sum += __shfl_xor(sum, 4);
      sum += __shfl_xor(sum, 8);
      l_[r] = l_[r] * f + sum;
      m_[r] = mn;
      P_s[prow + r][lrow]      = (short)u0;
      P_s[prow + r][16 + lrow] = (short)u1;
      P_s[prow + r][32 + lrow] = (short)u2;
      P_s[prow + r][48 + lrow] = (short)u3;
      #pragma unroll
      for (int nt = 0; nt < 16; ++nt) accO[nt][r] *= f;
    }

    // ---- PV: O[16q x 256c] += P[16q x 64k] * V[64k x 256c] ----
    bf16x8 pa0 = *(const bf16x8*)&P_s[w * 16 + lrow][lgrp * 8];
    bf16x8 pa1 = *(const bf16x8*)&P_s[w * 16 + lrow][32 + lgrp * 8];
    #pragma unroll
    for (int nt = 0; nt < 16; ++nt) {
      bf16x8 vb0 = *(const bf16x8*)&V_s[nt * 16 + lrow][lgrp * 8];
      bf16x8 vb1 = *(const bf16x8*)&V_s[nt * 16 + lrow][32 + lgrp * 8];
      accO[nt] = MFMA16(pa0, vb0, accO[nt]);
      accO[nt] = MFMA16(pa1, vb1, accO[nt]);
    }
  }

  // ---- epilogue: normalize, write O [q][c] fp32 ----
  float inv[4];
  #pragma unroll
  for (int r = 0; r < 4; ++r) inv[r] = 1.0f / l_[r];
  int qbase = qt * 64 + w * 16 + lgrp * 4;
  #pragma unroll
  for (int nt = 0; nt < 16; ++nt) {
    #pragma unroll
    for (int r = 0; r < 4; ++r) {
      O[(size_t)(qbase + r) * kC + nt * 16 + lrow] = accO[nt][r] * inv[r];
    }
  }
}

// ---------------------------------------------------------------------------
// Kernel 4: proj conv1x1 + residual via bf16 MFMA, hi/lo 3-term (fp32 output).
// ---------------------------------------------------------------------------
__global__ __launch_bounds__(256, 2)
void proj_mfma_kernel(const float* __restrict__ Ot, const float* __restrict__ wp,
                      const float* __restrict__ bp, const float* __restrict__ x,
                      float* __restrict__ out) {
  int bi = blockIdx.x;
  int pt = bi & 63;
  int b  = bi >> 6;
  int pbase = pt * 64;
  const float* Ob = Ot + (size_t)b * kHW * kC;   // [p][c]

  __shared__ short Ws_h[256][40];   // [o][c]
  __shared__ short Ws_l[256][40];
  __shared__ short Os_h[64][40];    // [p][c]
  __shared__ short Os_l[64][40];

  int tid  = threadIdx.x;
  int lane = tid & 63;
  int w    = tid >> 6;
  int lrow = lane & 15;
  int lgrp = lane >> 4;

  f32x4 acc[4][4];
  #pragma unroll
  for (int i = 0; i < 4; ++i)
    #pragma unroll
    for (int j = 0; j < 4; ++j) acc[i][j] = (f32x4){0.f, 0.f, 0.f, 0.f};

  for (int c0 = 0; c0 < kC; c0 += 32) {
    __syncthreads();
    {  // stage Wp row o=tid
      const float* s = wp + (size_t)tid * kC + c0;
      #pragma unroll
      for (int seg = 0; seg < 4; ++seg) {
        float4 a0 = *(const float4*)(s + seg * 8);
        float4 a1 = *(const float4*)(s + seg * 8 + 4);
        float v[8] = {a0.x, a0.y, a0.z, a0.w, a1.x, a1.y, a1.z, a1.w};
        short hh[8], ll[8];
        #pragma unroll
        for (int i = 0; i < 8; ++i) {
          unsigned short h = f2bf(v[i]);
          hh[i] = (short)h;
          ll[i] = (short)f2bf(v[i] - bf2f(h));
        }
        *(bf16x8*)&Ws_h[tid][seg * 8] = *(bf16x8*)hh;
        *(bf16x8*)&Ws_l[tid][seg * 8] = *(bf16x8*)ll;
      }
    }
    {  // stage O tile [64p][32c] hi/lo (Ot already [p][c])
      int p  = tid >> 2;
      int c8 = (tid & 3) * 8;
      const float* s = Ob + (size_t)(pbase + p) * kC + c0 + c8;
      float4 a0 = *(const float4*)(s);
      float4 a1 = *(const float4*)(s + 4);
      float v[8] = {a0.x, a0.y, a0.z, a0.w, a1.x, a1.y, a1.z, a1.w};
      short hh[8], ll[8];
      #pragma unroll
      for (int i = 0; i < 8; ++i) {
        unsigned short h = f2bf(v[i]);
        hh[i] = (short)h;
        ll[i] = (short)f2bf(v[i] - bf2f(h));
      }
      *(bf16x8*)&Os_h[p][c8] = *(bf16x8*)hh;
      *(bf16x8*)&Os_l[p][c8] = *(bf16x8*)ll;
    }
    __syncthreads();

    bf16x8 ah[4], al[4], bh[4], bl[4];
    #pragma unroll
    for (int mt = 0; mt < 4; ++mt) {
      ah[mt] = *(const bf16x8*)&Os_h[mt * 16 + lrow][lgrp * 8];
      al[mt] = *(const bf16x8*)&Os_l[mt * 16 + lrow][lgrp * 8];
    }
    #pragma unroll
    for (int nt = 0; nt < 4; ++nt) {
      bh[nt] = *(const bf16x8*)&Ws_h[w * 64 + nt * 16 + lrow][lgrp * 8];
      bl[nt] = *(const bf16x8*)&Ws_l[w * 64 + nt * 16 + lrow][lgrp * 8];
    }
    #pragma unroll
    for (int mt = 0; mt < 4; ++mt)
      #pragma unroll
      for (int nt = 0; nt < 4; ++nt) {
        acc[mt][nt] = MFMA16(ah[mt], bh[nt], acc[mt][nt]);
        acc[mt][nt] = MFMA16(al[mt], bh[nt], acc[mt][nt]);
        acc[mt][nt] = MFMA16(ah[mt], bl[nt], acc[mt][nt]);
      }
  }

  // epilogue: out[b][o][p] = acc + bp[o] + x[b][o][p]
  #pragma unroll
  for (int nt = 0; nt < 4; ++nt) {
    int o = w * 64 + nt * 16 + lrow;
    float bo = bp[o];
    #pragma unroll
    for (int mt = 0; mt < 4; ++mt) {
      int p0 = pbase + mt * 16 + lgrp * 4;
      const float* xr   = x   + ((size_t)b * kC + o) * kHW + p0;
      float*       orow = out + ((size_t)b * kC + o) * kHW + p0;
      float4 xv = *(const float4*)xr;
      float4 v = make_float4(acc[mt][nt][0] + bo + xv.x, acc[mt][nt][1] + bo + xv.y,
                             acc[mt][nt][2] + bo + xv.z, acc[mt][nt][3] + bo + xv.w);
      *(float4*)orow = v;
    }
  }
}

// ---------------------------------------------------------------------------
extern "C" void kernel_launch(void* const* d_in, const int* in_sizes, int n_in,
                              void* d_out, int out_size, void* d_ws, size_t ws_size,
                              hipStream_t stream) {
  (void)in_sizes; (void)n_in; (void)out_size;
  const float* x     = (const float*)d_in[0];
  const float* y     = (const float*)d_in[1];
  const float* gamma = (const float*)d_in[2];
  const float* beta  = (const float*)d_in[3];
  const float* wq    = (const float*)d_in[4];
  const float* bq    = (const float*)d_in[5];
  const float* wk    = (const float*)d_in[6];
  const float* bk    = (const float*)d_in[7];
  const float* wv    = (const float*)d_in[8];
  const float* bv    = (const float*)d_in[9];
  const float* wp    = (const float*)d_in[10];
  const float* bp    = (const float*)d_in[11];
  float* out = (float*)d_out;

  char* ws = (char*)d_ws;
  size_t bsz = (size_t)kB * kHW * kC * sizeof(unsigned short);  // 16 MB bf16 tensor
  size_t fsz = (size_t)kB * kHW * kC * sizeof(float);           // 32 MB fp32 tensor
  size_t need = 3 * bsz + fsz + 4 * (size_t)kB * kC * sizeof(float);
  if (ws_size < need) return;

  unsigned short* Qb = (unsigned short*)(ws);
  unsigned short* Kb = (unsigned short*)(ws + 1 * bsz);
  unsigned short* Vb = (unsigned short*)(ws + 2 * bsz);
  float* Ot     = (float*)(ws + 3 * bsz);
  float* scaleX = (float*)(ws + 3 * bsz + fsz);
  float* shiftX = scaleX + kB * kC;
  float* scaleY = shiftX + kB * kC;
  float* shiftY = scaleY + kB * kC;

  gn_stats_kernel<<<dim3(64), dim3(256), 0, stream>>>(
      x, y, gamma, beta, scaleX, shiftX, scaleY, shiftY);
  qkv_mfma_kernel<<<dim3(kB * 64, 3), dim3(256), 0, stream>>>(
      x, y, wq, bq, wk, bk, wv, bv, scaleX, shiftX, scaleY, shiftY,
      Qb, Kb, Vb);
  flash_mfma_kernel<<<dim3(kB * 64), dim3(256), 0, stream>>>(Qb, Kb, Vb, Ot);
  proj_mfma_kernel<<<dim3(kB * 64), dim3(256), 0, stream>>>(Ot, wp, bp, x, out);
}

// Round 10
// 466.238 us; speedup vs baseline: 2.6461x; 1.2862x over previous
//
#include <hip/hip_runtime.h>
#include <math.h>

// AttnBlock fused pipeline, round 10: flash identical to r9 (banked win);
// non-flash de-redundancy: precomputed bf16 weights (wprep), copy-only W
// staging, plain-bf16 proj, 2-stage GroupNorm stats.
//   x,y: [8, 256, 64, 64] fp32; GN groups=4 eps=1e-6; 4 conv1x1 weights [256,256].
// Fragment convention (HW-validated r3/r5/r7/r9):
//   A-frag: m = lane&15, k-slice = (lane>>4)*8 ; B-frag: n = lane&15, same k
//   D: col = lane&15, row = (lane>>4)*4 + reg.

namespace {
constexpr int kB   = 8;
constexpr int kC   = 256;
constexpr int kCPG = 64;
constexpr int kHW  = 4096;
constexpr float kEps = 1e-6f;
}

typedef short bf16x8 __attribute__((ext_vector_type(8)));   // 8 bf16 in 4 VGPRs
typedef float f32x4  __attribute__((ext_vector_type(4)));

#define MFMA16(a, b, c) __builtin_amdgcn_mfma_f32_16x16x32_bf16((a), (b), (c), 0, 0, 0)

__device__ __forceinline__ unsigned short f2bf(float v) {   // RNE fp32 -> bf16 bits
  unsigned u = __float_as_uint(v);
  u += 0x7FFFu + ((u >> 16) & 1u);
  return (unsigned short)(u >> 16);
}
__device__ __forceinline__ float bf2f(unsigned short h) {
  return __uint_as_float(((unsigned)h) << 16);
}

// ---------------------------------------------------------------------------
// Kernel 0: one-shot weight conversion fp32 -> bf16 (64 blocks x 256 thr).
// ---------------------------------------------------------------------------
__global__ __launch_bounds__(256)
void wprep_kernel(const float* __restrict__ wq, const float* __restrict__ wk,
                  const float* __restrict__ wv, const float* __restrict__ wp,
                  unsigned short* __restrict__ Wqb, unsigned short* __restrict__ Wkb,
                  unsigned short* __restrict__ Wvb, unsigned short* __restrict__ Wpb) {
  int i = (blockIdx.x * 256 + threadIdx.x) * 4;   // 16384 threads x 4 = 65536
  {
    float4 a = *(const float4*)(wq + i);
    ushort4 h = {f2bf(a.x), f2bf(a.y), f2bf(a.z), f2bf(a.w)};
    *(ushort4*)(Wqb + i) = h;
  }
  {
    float4 a = *(const float4*)(wk + i);
    ushort4 h = {f2bf(a.x), f2bf(a.y), f2bf(a.z), f2bf(a.w)};
    *(ushort4*)(Wkb + i) = h;
  }
  {
    float4 a = *(const float4*)(wv + i);
    ushort4 h = {f2bf(a.x), f2bf(a.y), f2bf(a.z), f2bf(a.w)};
    *(ushort4*)(Wvb + i) = h;
  }
  {
    float4 a = *(const float4*)(wp + i);
    ushort4 h = {f2bf(a.x), f2bf(a.y), f2bf(a.z), f2bf(a.w)};
    *(ushort4*)(Wpb + i) = h;
  }
}

// ---------------------------------------------------------------------------
// Kernel 1a: GroupNorm partial sums. 512 blocks = 64 groups x 8 chunks.
// ---------------------------------------------------------------------------
__global__ __launch_bounds__(256)
void gn_part_kernel(const float* __restrict__ x, const float* __restrict__ y,
                    float* __restrict__ part) {
  int blk   = blockIdx.x;
  int grp   = blk >> 3;            // t*32 + b*4 + g
  int chunk = blk & 7;
  int g = grp & 3;
  int b = (grp >> 2) & 7;
  int t = grp >> 5;
  const float* src = (t == 0 ? x : y) + ((size_t)b * kC + (size_t)g * kCPG) * kHW
                     + (size_t)chunk * 32768;
  float sum = 0.f, ssq = 0.f;
  for (int i = threadIdx.x * 4; i < 32768; i += 1024) {
    float4 v = *(const float4*)(src + i);
    sum += v.x + v.y + v.z + v.w;
    ssq += v.x * v.x + v.y * v.y + v.z * v.z + v.w * v.w;
  }
  #pragma unroll
  for (int off = 32; off > 0; off >>= 1) {
    sum += __shfl_down(sum, off);
    ssq += __shfl_down(ssq, off);
  }
  __shared__ float rs[4], rq[4];
  int lane = threadIdx.x & 63, w = threadIdx.x >> 6;
  if (lane == 0) { rs[w] = sum; rq[w] = ssq; }
  __syncthreads();
  if (threadIdx.x == 0) {
    part[blk * 2]     = rs[0] + rs[1] + rs[2] + rs[3];
    part[blk * 2 + 1] = rq[0] + rq[1] + rq[2] + rq[3];
  }
}

// ---------------------------------------------------------------------------
// Kernel 1b: GroupNorm finalize -> per-(tensor,b,c) scale/shift. 64 x 64thr.
// ---------------------------------------------------------------------------
__global__ __launch_bounds__(64)
void gn_fin_kernel(const float* __restrict__ part,
                   const float* __restrict__ gamma, const float* __restrict__ beta,
                   float* __restrict__ scaleX, float* __restrict__ shiftX,
                   float* __restrict__ scaleY, float* __restrict__ shiftY) {
  int grp = blockIdx.x;            // t*32 + b*4 + g
  int g = grp & 3;
  int b = (grp >> 2) & 7;
  int t = grp >> 5;
  float s = 0.f, q = 0.f;
  #pragma unroll
  for (int j = 0; j < 8; ++j) {
    s += part[(grp * 8 + j) * 2];
    q += part[(grp * 8 + j) * 2 + 1];
  }
  const float N = (float)(kCPG * kHW);
  float mean = s / N;
  float var  = q / N - mean * mean;
  float rstd = rsqrtf(var + kEps);
  int c = g * kCPG + threadIdx.x;
  float sc = gamma[c] * rstd;
  float sh = beta[c] - mean * sc;
  if (t == 0) { scaleX[b * kC + c] = sc; shiftX[b * kC + c] = sh; }
  else        { scaleY[b * kC + c] = sc; shiftY[b * kC + c] = sh; }
}

// ---------------------------------------------------------------------------
// Kernel 2: QKV conv1x1 via plain bf16 MFMA; W staged by pure int4 copy.
//   Q/K: A=W(m=o), B=Xn(n=p) -> store [p][o].  V: A=Xn(m=p), B=W(n=o) -> [o][p].
//   GN affine fused into X staging; 1/16 score scale folded into Q.
// ---------------------------------------------------------------------------
__global__ __launch_bounds__(256, 2)
void qkv_mfma_kernel(const float* __restrict__ x, const float* __restrict__ y,
                     const unsigned short* __restrict__ Wqb,
                     const unsigned short* __restrict__ Wkb,
                     const unsigned short* __restrict__ Wvb,
                     const float* __restrict__ bq, const float* __restrict__ bk,
                     const float* __restrict__ bv,
                     const float* __restrict__ scaleX, const float* __restrict__ shiftX,
                     const float* __restrict__ scaleY, const float* __restrict__ shiftY,
                     unsigned short* __restrict__ Qo, unsigned short* __restrict__ Ko,
                     unsigned short* __restrict__ Vo) {
  int z  = blockIdx.y;                 // 0=q (from x), 1=k, 2=v (from y)
  int bi = blockIdx.x;
  int pt = bi & 63;
  int b  = bi >> 6;
  int pbase = pt * 64;
  const float* X = (z == 0 ? x : y) + (size_t)b * kC * kHW;
  const unsigned short* Wb = (z == 0 ? Wqb : (z == 1 ? Wkb : Wvb));
  const float* bias = (z == 0 ? bq : (z == 1 ? bk : bv));
  const float* SC   = (z == 0 ? scaleX : scaleY) + b * kC;
  const float* SH   = (z == 0 ? shiftX : shiftY) + b * kC;

  __shared__ short Ws[256][40];   // [o][c] +8 pad
  __shared__ short Xs[64][40];    // [p][c] +8 pad
  __shared__ float Xt[32][68];    // fp32 transpose staging [c][p]

  int tid  = threadIdx.x;
  int lane = tid & 63;
  int w    = tid >> 6;
  int lrow = lane & 15;
  int lgrp = lane >> 4;

  f32x4 acc[4][4];
  #pragma unroll
  for (int i = 0; i < 4; ++i)
    #pragma unroll
    for (int j = 0; j < 4; ++j) acc[i][j] = (f32x4){0.f, 0.f, 0.f, 0.f};

  for (int c0 = 0; c0 < kC; c0 += 32) {
    __syncthreads();
    {  // ---- stage W row o=tid, 32 c: pure copy ----
      const int4* s4 = (const int4*)(Wb + (size_t)tid * kC + c0);
      *(int4*)&Ws[tid][0]  = s4[0];
      *(int4*)&Ws[tid][8]  = s4[1];
      *(int4*)&Ws[tid][16] = s4[2];
      *(int4*)&Ws[tid][24] = s4[3];
    }
    {  // ---- stage X [32c][64p] normalized fp32 ----
      int c  = tid >> 3;
      int p8 = (tid & 7) * 8;
      const float* s = X + (size_t)(c0 + c) * kHW + pbase + p8;
      float sc = SC[c0 + c], sh = SH[c0 + c];
      float4 a0 = *(const float4*)(s);
      float4 a1 = *(const float4*)(s + 4);
      float4 r0 = make_float4(fmaf(a0.x, sc, sh), fmaf(a0.y, sc, sh), fmaf(a0.z, sc, sh), fmaf(a0.w, sc, sh));
      float4 r1 = make_float4(fmaf(a1.x, sc, sh), fmaf(a1.y, sc, sh), fmaf(a1.z, sc, sh), fmaf(a1.w, sc, sh));
      *(float4*)&Xt[c][p8]     = r0;
      *(float4*)&Xt[c][p8 + 4] = r1;
    }
    __syncthreads();
    {  // ---- transpose Xt -> Xs[p][c] ----
      int p  = tid & 63;
      int cs = (tid >> 6) * 8;
      short hh[8];
      #pragma unroll
      for (int i = 0; i < 8; ++i) hh[i] = (short)f2bf(Xt[cs + i][p]);
      *(bf16x8*)&Xs[p][cs] = *(bf16x8*)hh;
    }
    __syncthreads();

    if (z < 2) {
      bf16x8 am[4], bn[4];
      #pragma unroll
      for (int mt = 0; mt < 4; ++mt)
        am[mt] = *(const bf16x8*)&Ws[w * 64 + mt * 16 + lrow][lgrp * 8];
      #pragma unroll
      for (int nt = 0; nt < 4; ++nt)
        bn[nt] = *(const bf16x8*)&Xs[nt * 16 + lrow][lgrp * 8];
      #pragma unroll
      for (int mt = 0; mt < 4; ++mt)
        #pragma unroll
        for (int nt = 0; nt < 4; ++nt)
          acc[mt][nt] = MFMA16(am[mt], bn[nt], acc[mt][nt]);
    } else {
      bf16x8 am[4], bn[4];
      #pragma unroll
      for (int mt = 0; mt < 4; ++mt)
        am[mt] = *(const bf16x8*)&Xs[mt * 16 + lrow][lgrp * 8];
      #pragma unroll
      for (int nt = 0; nt < 4; ++nt)
        bn[nt] = *(const bf16x8*)&Ws[w * 64 + nt * 16 + lrow][lgrp * 8];
      #pragma unroll
      for (int mt = 0; mt < 4; ++mt)
        #pragma unroll
        for (int nt = 0; nt < 4; ++nt)
          acc[mt][nt] = MFMA16(am[mt], bn[nt], acc[mt][nt]);
    }
  }

  // ---- epilogue ----
  if (z < 2) {
    float osc = (z == 0) ? 0.0625f : 1.0f;
    unsigned short* T = ((z == 0) ? Qo : Ko) + (size_t)b * kHW * kC;
    #pragma unroll
    for (int mt = 0; mt < 4; ++mt) {
      int o0 = w * 64 + mt * 16 + lgrp * 4;
      float4 b4 = *(const float4*)&bias[o0];
      #pragma unroll
      for (int nt = 0; nt < 4; ++nt) {
        int p = pbase + nt * 16 + lrow;
        ushort4 hh;
        hh.x = f2bf((acc[mt][nt][0] + b4.x) * osc);
        hh.y = f2bf((acc[mt][nt][1] + b4.y) * osc);
        hh.z = f2bf((acc[mt][nt][2] + b4.z) * osc);
        hh.w = f2bf((acc[mt][nt][3] + b4.w) * osc);
        *(ushort4*)&T[(size_t)p * kC + o0] = hh;
      }
    }
  } else {
    unsigned short* Vb = Vo + (size_t)b * kHW * kC;   // [o][p]
    #pragma unroll
    for (int nt = 0; nt < 4; ++nt) {
      int o = w * 64 + nt * 16 + lrow;
      float bo = bias[o];
      #pragma unroll
      for (int mt = 0; mt < 4; ++mt) {
        int p0 = pbase + mt * 16 + lgrp * 4;
        ushort4 hh;
        hh.x = f2bf(acc[mt][nt][0] + bo);
        hh.y = f2bf(acc[mt][nt][1] + bo);
        hh.z = f2bf(acc[mt][nt][2] + bo);
        hh.w = f2bf(acc[mt][nt][3] + bo);
        *(ushort4*)&Vb[(size_t)o * kHW + p0] = hh;
      }
    }
  }
}

// ---------------------------------------------------------------------------
// Kernel 3: MFMA flash attention — BYTE-IDENTICAL to round 9 (banked).
// ---------------------------------------------------------------------------
__global__ __launch_bounds__(256, 2)
void flash_mfma_kernel(const unsigned short* __restrict__ Q,
                       const unsigned short* __restrict__ K,
                       const unsigned short* __restrict__ V,
                       float* __restrict__ Ot) {
  int bid = blockIdx.x;
  int b  = bid & 7;                 // one batch per XCD: K/V stay L2-resident
  int qt = bid >> 3;
  const size_t toff = (size_t)b * kHW * kC;
  const unsigned short* Qb = Q + toff;   // [q][c]
  const unsigned short* Kb = K + toff;   // [k][c]
  const unsigned short* Vb = V + toff;   // [c][k]
  float* O = Ot + toff;                  // [q][c]

  __shared__ short K_s[64][264];   // [key][c] +8 pad   (33.8 KB)
  __shared__ short V_s[256][72];   // [c][key] +8 pad   (36.9 KB)
  __shared__ short P_s[64][72];    // [q][key] +8 pad   (9.2 KB, wave-private)

  int tid  = threadIdx.x;
  int lane = tid & 63;
  int w    = tid >> 6;
  int lrow = lane & 15;
  int lgrp = lane >> 4;

  bf16x8 qf[8];
  {
    int qrow = qt * 64 + w * 16 + lrow;
    const unsigned short* qb = Qb + (size_t)qrow * kC + lgrp * 8;
    #pragma unroll
    for (int cc = 0; cc < 8; ++cc) qf[cc] = *(const bf16x8*)(qb + cc * 32);
  }

  int krow0 = tid >> 5;              // 0..7  (+rep*8 -> 64 rows)
  int kcol  = (tid & 31) * 8;
  int vc0   = tid >> 3;              // 0..31 (+rep*32 -> 256 rows)
  int vpart = (tid & 7) * 8;

  f32x4 accO[16];
  #pragma unroll
  for (int nt = 0; nt < 16; ++nt) accO[nt] = (f32x4){0.f, 0.f, 0.f, 0.f};
  float m_[4], l_[4];
  #pragma unroll
  for (int r = 0; r < 4; ++r) { m_[r] = -1e30f; l_[r] = 0.f; }

  for (int kt = 0; kt < 64; ++kt) {
    int kbase = kt * 64;
    __syncthreads();
    #pragma unroll
    for (int rep = 0; rep < 8; ++rep) {
      *(int4*)&K_s[krow0 + rep * 8][kcol] =
          *(const int4*)(Kb + (size_t)(kbase + krow0 + rep * 8) * kC + kcol);
      *(int4*)&V_s[vc0 + rep * 32][vpart] =
          *(const int4*)(Vb + (size_t)(vc0 + rep * 32) * kHW + kbase + vpart);
    }
    __syncthreads();

    f32x4 s0 = (f32x4){0.f, 0.f, 0.f, 0.f};
    f32x4 s1 = (f32x4){0.f, 0.f, 0.f, 0.f};
    f32x4 s2 = (f32x4){0.f, 0.f, 0.f, 0.f};
    f32x4 s3 = (f32x4){0.f, 0.f, 0.f, 0.f};
    #pragma unroll
    for (int cc = 0; cc < 8; ++cc) {
      int coff = cc * 32 + lgrp * 8;
      bf16x8 k0 = *(const bf16x8*)&K_s[lrow][coff];
      bf16x8 k1 = *(const bf16x8*)&K_s[16 + lrow][coff];
      bf16x8 k2 = *(const bf16x8*)&K_s[32 + lrow][coff];
      bf16x8 k3 = *(const bf16x8*)&K_s[48 + lrow][coff];
      s0 = MFMA16(qf[cc], k0, s0);
      s1 = MFMA16(qf[cc], k1, s1);
      s2 = MFMA16(qf[cc], k2, s2);
      s3 = MFMA16(qf[cc], k3, s3);
    }

    int prow = w * 16 + lgrp * 4;
    #pragma unroll
    for (int r = 0; r < 4; ++r) {
      float mx = fmaxf(fmaxf(s0[r], s1[r]), fmaxf(s2[r], s3[r]));
      mx = fmaxf(mx, __shfl_xor(mx, 1));
      mx = fmaxf(mx, __shfl_xor(mx, 2));
      mx = fmaxf(mx, __shfl_xor(mx, 4));
      mx = fmaxf(mx, __shfl_xor(mx, 8));
      float mn = fmaxf(m_[r], mx);
      float f  = __expf(m_[r] - mn);
      unsigned short u0 = f2bf(__expf(s0[r] - mn));
      unsigned short u1 = f2bf(__expf(s1[r] - mn));
      unsigned short u2 = f2bf(__expf(s2[r] - mn));
      unsigned short u3 = f2bf(__expf(s3[r] - mn));
      float sum = (bf2f(u0) + bf2f(u1)) + (bf2f(u2) + bf2f(u3));
      sum += __shfl_xor(sum, 1);
      sum += __shfl_xor(sum, 2);
      sum += __shfl_xor(sum, 4);
      sum += __shfl_xor(sum, 8);
      l_[r] = l_[r] * f + sum;
      m_[r] = mn;
      P_s[prow + r][lrow]      = (short)u0;
      P_s[prow + r][16 + lrow] = (short)u1;
      P_s[prow + r][32 + lrow] = (short)u2;
      P_s[prow + r][48 + lrow] = (short)u3;
      #pragma unroll
      for (int nt = 0; nt < 16; ++nt) accO[nt][r] *= f;
    }

    bf16x8 pa0 = *(const bf16x8*)&P_s[w * 16 + lrow][lgrp * 8];
    bf16x8 pa1 = *(const bf16x8*)&P_s[w * 16 + lrow][32 + lgrp * 8];
    #pragma unroll
    for (int nt = 0; nt < 16; ++nt) {
      bf16x8 vb0 = *(const bf16x8*)&V_s[nt * 16 + lrow][lgrp * 8];
      bf16x8 vb1 = *(const bf16x8*)&V_s[nt * 16 + lrow][32 + lgrp * 8];
      accO[nt] = MFMA16(pa0, vb0, accO[nt]);
      accO[nt] = MFMA16(pa1, vb1, accO[nt]);
    }
  }

  float inv[4];
  #pragma unroll
  for (int r = 0; r < 4; ++r) inv[r] = 1.0f / l_[r];
  int qbase = qt * 64 + w * 16 + lgrp * 4;
  #pragma unroll
  for (int nt = 0; nt < 16; ++nt) {
    #pragma unroll
    for (int r = 0; r < 4; ++r) {
      O[(size_t)(qbase + r) * kC + nt * 16 + lrow] = accO[nt][r] * inv[r];
    }
  }
}

// ---------------------------------------------------------------------------
// Kernel 4: proj conv1x1 + residual, plain bf16 MFMA (W precomputed).
//   A = O_attn[p][c] (m=p), B = Wp[o][c] (n=o) -> D[p][o]; out[o][p] f32.
// ---------------------------------------------------------------------------
__global__ __launch_bounds__(256, 2)
void proj_mfma_kernel(const float* __restrict__ Ot,
                      const unsigned short* __restrict__ Wpb,
                      const float* __restrict__ bp, const float* __restrict__ x,
                      float* __restrict__ out) {
  int bi = blockIdx.x;
  int pt = bi & 63;
  int b  = bi >> 6;
  int pbase = pt * 64;
  const float* Ob = Ot + (size_t)b * kHW * kC;   // [p][c]

  __shared__ short Ws[256][40];   // [o][c]
  __shared__ short Os[64][40];    // [p][c]

  int tid  = threadIdx.x;
  int lane = tid & 63;
  int w    = tid >> 6;
  int lrow = lane & 15;
  int lgrp = lane >> 4;

  f32x4 acc[4][4];
  #pragma unroll
  for (int i = 0; i < 4; ++i)
    #pragma unroll
    for (int j = 0; j < 4; ++j) acc[i][j] = (f32x4){0.f, 0.f, 0.f, 0.f};

  for (int c0 = 0; c0 < kC; c0 += 32) {
    __syncthreads();
    {  // stage Wp row o=tid: pure copy
      const int4* s4 = (const int4*)(Wpb + (size_t)tid * kC + c0);
      *(int4*)&Ws[tid][0]  = s4[0];
      *(int4*)&Ws[tid][8]  = s4[1];
      *(int4*)&Ws[tid][16] = s4[2];
      *(int4*)&Ws[tid][24] = s4[3];
    }
    {  // stage O tile [64p][32c] bf16
      int p  = tid >> 2;
      int c8 = (tid & 3) * 8;
      const float* s = Ob + (size_t)(pbase + p) * kC + c0 + c8;
      float4 a0 = *(const float4*)(s);
      float4 a1 = *(const float4*)(s + 4);
      short hh[8] = {(short)f2bf(a0.x), (short)f2bf(a0.y), (short)f2bf(a0.z), (short)f2bf(a0.w),
                     (short)f2bf(a1.x), (short)f2bf(a1.y), (short)f2bf(a1.z), (short)f2bf(a1.w)};
      *(bf16x8*)&Os[p][c8] = *(bf16x8*)hh;
    }
    __syncthreads();

    bf16x8 am[4], bn[4];
    #pragma unroll
    for (int mt = 0; mt < 4; ++mt)
      am[mt] = *(const bf16x8*)&Os[mt * 16 + lrow][lgrp * 8];
    #pragma unroll
    for (int nt = 0; nt < 4; ++nt)
      bn[nt] = *(const bf16x8*)&Ws[w * 64 + nt * 16 + lrow][lgrp * 8];
    #pragma unroll
    for (int mt = 0; mt < 4; ++mt)
      #pragma unroll
      for (int nt = 0; nt < 4; ++nt)
        acc[mt][nt] = MFMA16(am[mt], bn[nt], acc[mt][nt]);
  }

  // epilogue: out[b][o][p] = acc + bp[o] + x[b][o][p]
  #pragma unroll
  for (int nt = 0; nt < 4; ++nt) {
    int o = w * 64 + nt * 16 + lrow;
    float bo = bp[o];
    #pragma unroll
    for (int mt = 0; mt < 4; ++mt) {
      int p0 = pbase + mt * 16 + lgrp * 4;
      const float* xr   = x   + ((size_t)b * kC + o) * kHW + p0;
      float*       orow = out + ((size_t)b * kC + o) * kHW + p0;
      float4 xv = *(const float4*)xr;
      float4 v = make_float4(acc[mt][nt][0] + bo + xv.x, acc[mt][nt][1] + bo + xv.y,
                             acc[mt][nt][2] + bo + xv.z, acc[mt][nt][3] + bo + xv.w);
      *(float4*)orow = v;
    }
  }
}

// ---------------------------------------------------------------------------
extern "C" void kernel_launch(void* const* d_in, const int* in_sizes, int n_in,
                              void* d_out, int out_size, void* d_ws, size_t ws_size,
                              hipStream_t stream) {
  (void)in_sizes; (void)n_in; (void)out_size;
  const float* x     = (const float*)d_in[0];
  const float* y     = (const float*)d_in[1];
  const float* gamma = (const float*)d_in[2];
  const float* beta  = (const float*)d_in[3];
  const float* wq    = (const float*)d_in[4];
  const float* bq    = (const float*)d_in[5];
  const float* wk    = (const float*)d_in[6];
  const float* bk    = (const float*)d_in[7];
  const float* wv    = (const float*)d_in[8];
  const float* bv    = (const float*)d_in[9];
  const float* wp    = (const float*)d_in[10];
  const float* bp    = (const float*)d_in[11];
  float* out = (float*)d_out;

  char* ws = (char*)d_ws;
  size_t bsz = (size_t)kB * kHW * kC * sizeof(unsigned short);  // 16 MB bf16 tensor
  size_t fsz = (size_t)kB * kHW * kC * sizeof(float);           // 32 MB fp32 tensor
  size_t wsz = (size_t)kC * kC * sizeof(unsigned short);        // 128 KB bf16 weight
  size_t need = 3 * bsz + fsz + 4 * wsz
              + 4 * (size_t)kB * kC * sizeof(float) + 1024 * sizeof(float);
  if (ws_size < need) return;

  unsigned short* Qb  = (unsigned short*)(ws);
  unsigned short* Kb  = (unsigned short*)(ws + 1 * bsz);
  unsigned short* Vb  = (unsigned short*)(ws + 2 * bsz);
  float*          Ot  = (float*)(ws + 3 * bsz);
  unsigned short* Wqb = (unsigned short*)(ws + 3 * bsz + fsz);
  unsigned short* Wkb = (unsigned short*)(ws + 3 * bsz + fsz + 1 * wsz);
  unsigned short* Wvb = (unsigned short*)(ws + 3 * bsz + fsz + 2 * wsz);
  unsigned short* Wpb = (unsigned short*)(ws + 3 * bsz + fsz + 3 * wsz);
  float* scaleX = (float*)(ws + 3 * bsz + fsz + 4 * wsz);
  float* shiftX = scaleX + kB * kC;
  float* scaleY = shiftX + kB * kC;
  float* shiftY = scaleY + kB * kC;
  float* part   = shiftY + kB * kC;   // 512 x 2 floats

  wprep_kernel<<<dim3(64), dim3(256), 0, stream>>>(
      wq, wk, wv, wp, Wqb, Wkb, Wvb, Wpb);
  gn_part_kernel<<<dim3(512), dim3(256), 0, stream>>>(x, y, part);
  gn_fin_kernel<<<dim3(64), dim3(64), 0, stream>>>(
      part, gamma, beta, scaleX, shiftX, scaleY, shiftY);
  qkv_mfma_kernel<<<dim3(kB * 64, 3), dim3(256), 0, stream>>>(
      x, y, Wqb, Wkb, Wvb, bq, bk, bv, scaleX, shiftX, scaleY, shiftY,
      Qb, Kb, Vb);
  flash_mfma_kernel<<<dim3(kB * 64), dim3(256), 0, stream>>>(Qb, Kb, Vb, Ot);
  proj_mfma_kernel<<<dim3(kB * 64), dim3(256), 0, stream>>>(Ot, Wpb, bp, x, out);
}